// Round 10
// baseline (1626.196 us; speedup 1.0000x reference)
//
#include <hip/hip_runtime.h>

typedef _Float16 f16;
typedef _Float16 f16x4 __attribute__((ext_vector_type(4)));
typedef _Float16 f16x8 __attribute__((ext_vector_type(8)));
typedef float f32x4 __attribute__((ext_vector_type(4)));

#define TLEN 2048
#define TPAD 2050     // gates3 time extent (2 pad steps: prefetch needs no clamp)
#define NCOL 640      // padded columns: 160 units x 4 gates, col = u*4 + G
#define GSTEP (16 * NCOL)   // f16 elements per timestep in gates3 [t][b][col]
#define K1   1.4426950408889634f   // log2(e)
#define K2   2.8853900817779268f   // 2*log2(e)

__device__ __forceinline__ f16x8 as_f16x8(f32x4 v) {
    union { f32x4 f; f16x8 h; } u; u.f = v; return u.h;
}

// ---------------------------------------------------------------------------
// Prep: MFMA fragment-ordered fp16 w_ih / w_hh, columns ordered
// col = unit*4 + gate, PRE-SCALED per gate (i,f,o: -K1; g: +K2) so the
// scan's exp2 args need no multiply.  Fragment layout:
// [nt(40)][kt(5)][lane(64)][e(8)], col = nt*16 + (lane&15),
// k = kt*32 + (lane>>4)*8 + e.  biasp[col] gets the same scale.
// ---------------------------------------------------------------------------
__global__ void prep_weights(const float* __restrict__ w_ih,
                             const float* __restrict__ w_hh,
                             const float* __restrict__ b_ih,
                             const float* __restrict__ b_hh,
                             f16* __restrict__ wihf, f16* __restrict__ whhf,
                             float* __restrict__ biasp)
{
    const int idx = blockIdx.x * blockDim.x + threadIdx.x;
    const int stride = gridDim.x * blockDim.x;
    for (int i = idx; i < 40 * 5 * 64 * 8; i += stride) {
        const int e = i & 7;
        const int lane = (i >> 3) & 63;
        const int kt = (i >> 9) % 5;
        const int nt = i / 2560;
        const int colg = nt * 16 + (lane & 15);
        const int u = colg >> 2, G = colg & 3;
        const int k = kt * 32 + (lane >> 4) * 8 + e;
        const float sc = (G == 2) ? K2 : -K1;
        f16 vi = (f16)0.f, vh = (f16)0.f;
        if (u < 150) {
            const int row = G * 150 + u;
            if (k < 144) vi = (f16)(w_ih[row * 144 + k] * sc);
            if (k < 150) vh = (f16)(w_hh[row * 150 + k] * sc);
        }
        wihf[i] = vi;
        whhf[i] = vh;
    }
    for (int i = idx; i < NCOL; i += stride) {
        const int u = i >> 2, G = i & 3;
        const float sc = (G == 2) ? K2 : -K1;
        biasp[i] = (u < 150) ? (b_ih[G * 150 + u] + b_hh[G * 150 + u]) * sc : 0.f;
    }
}

// ---------------------------------------------------------------------------
// Conv 3x3 VALID (17->4) + bias + ReLU.  4 (b,t) tiles per 256-thread block.
// Writes y in [t*16+b][160] fp16 (K padded 144->160 with zeros).
// ---------------------------------------------------------------------------
__global__ __launch_bounds__(256) void conv_relu(
    const float* __restrict__ in, const float* __restrict__ cw,
    const float* __restrict__ cb, f16* __restrict__ y)
{
    __shared__ float s_in[4][1088];
    __shared__ float s_w[612];
    __shared__ float s_b[4];
    const int tid = threadIdx.x, sub = tid >> 6, lt = tid & 63;
    const int bt = blockIdx.x * 4 + sub;
    const float* ip = in + (size_t)bt * 1088;
    #pragma unroll
    for (int i = 0; i < 17; ++i) s_in[sub][lt + i * 64] = ip[lt + i * 64];
    for (int i = tid; i < 612; i += 256) s_w[i] = cw[i];
    if (tid < 4) s_b[tid] = cb[tid];
    __syncthreads();
    const int b = bt >> 11, t = bt & 2047;
    f16* yr = y + (size_t)(t * 16 + b) * 160;
    for (int i = lt; i < 160; i += 64) {
        float v = 0.f;
        if (i < 144) {
            const int oc = i / 36, rr = i % 36, oy = rr / 6, ox = rr % 6;
            float acc = s_b[oc];
            const float* wp = s_w + oc * 153;
            const float* bp = &s_in[sub][oy * 8 + ox];
            #pragma unroll
            for (int ic = 0; ic < 17; ++ic)
                #pragma unroll
                for (int ky = 0; ky < 3; ++ky)
                    #pragma unroll
                    for (int kx = 0; kx < 3; ++kx)
                        acc += bp[ic * 64 + ky * 8 + kx] * wp[ic * 9 + ky * 3 + kx];
            v = fmaxf(acc, 0.f);
        }
        yr[i] = (f16)v;
    }
}

// ---------------------------------------------------------------------------
// gates_x = y @ w_ih_scaled^T + bias_scaled.  One block (10 waves) per 8
// timesteps: w_ih fragments + bias hoisted into registers once, then 8 t's
// of {load A, 20 MFMA, store} -- cuts wihf L2 re-reads 8x vs one-t blocks.
// Output layout [t][b(16)][col(640)] flat f16.
// ---------------------------------------------------------------------------
__global__ __launch_bounds__(640, 1) void gates_gemm(
    const f16* __restrict__ y, const f16* __restrict__ wihf,
    const float* __restrict__ biasp, f16* __restrict__ gates3)
{
    const int tid = threadIdx.x, wv = tid >> 6, lane = tid & 63;
    const int col = lane & 15, grp = lane >> 4;
    const int t0 = blockIdx.x * 8;

    f16x8 bfr[4][5];
    float bb[4];
    #pragma unroll
    for (int i = 0; i < 4; ++i) {
        const int nt = wv * 4 + i;
        const f16* wf = wihf + (size_t)(nt * 5) * 512;
        #pragma unroll
        for (int kt = 0; kt < 5; ++kt)
            bfr[i][kt] = *(const f16x8*)(wf + kt * 512 + lane * 8);
        bb[i] = biasp[nt * 16 + col];
    }

    for (int t = t0; t < t0 + 8; ++t) {
        f16x8 a[5];
        const f16* yr = y + (size_t)(t * 16 + col) * 160;
        #pragma unroll
        for (int kt = 0; kt < 5; ++kt)
            a[kt] = *(const f16x8*)(yr + kt * 32 + grp * 8);
        #pragma unroll
        for (int i = 0; i < 4; ++i) {
            const int nt = wv * 4 + i;
            f32x4 acc = {0.f, 0.f, 0.f, 0.f};
            #pragma unroll
            for (int kt = 0; kt < 5; ++kt)
                acc = __builtin_amdgcn_mfma_f32_16x16x32_f16(a[kt], bfr[i][kt], acc, 0, 0, 0);
            const int colg = nt * 16 + col;
            #pragma unroll
            for (int r = 0; r < 4; ++r)
                gates3[((size_t)(t * 16 + grp * 4 + r)) * NCOL + colg] = (f16)(acc[r] + bb[i]);
        }
    }
}

// ---------------------------------------------------------------------------
// Batch-parallel persistent LSTM scan: 16 WGs (one batch row each), 256
// threads = 4 waves = 1 wave/SIMD.  Wave w owns 10 tiles (units 40w..40w+39);
// per-SIMD MFMA stays at the 50/step pipe floor, but act / ds_read / select
// / write streams are issued ONCE per SIMD instead of twice (the 8-wave
// version's 2 lockstep waves duplicated all non-MFMA issue).  A = w_hh
// fragments resident (10x5 f32x4 = 200 VGPRs; 1 wave/SIMD budget 512).
// B = h broadcast from linear 160-f16 LDS double buffer (conflict-free).
// Each lane loads ONE f16x4 of gates_x (its own unit), converted in the
// B-read shadow; shared C-init for all tiles' kt=0 (unselected discarded).
// ---------------------------------------------------------------------------
__device__ __forceinline__ void lstm_stepZ(
    int t, f16x4& pfu, f16x4& pfc, const f16*& pLoad,
    const f32x4 (&afrag)[10][5], f16* hbufs, float& cst,
    int grp, int sel, bool wr, int wel)
{
    const int cur = t & 1;

    // 1) Issue B-fragment reads (broadcast, conflict-free).
    const f16* hr = hbufs + cur * 160 + grp * 8;
    f16x8 bf[5];
    #pragma unroll
    for (int kt = 0; kt < 5; ++kt)
        bf[kt] = *(const f16x8*)(hr + kt * 32);

    // 2) In the read shadow: convert this step's unit-gates (loaded 2 steps
    //    ago) and refill the slot with step t+2.
    f32x4 gxf;
    gxf[0] = (float)pfu[0];
    gxf[1] = (float)pfu[1];
    gxf[2] = (float)pfu[2];
    gxf[3] = (float)pfu[3];
    pfc = *(const f16x4*)pLoad;
    pLoad += GSTEP;

    // 3) MFMA: kt=0 uses gxf as C-in for ALL tiles; kt=1..4 chain.
    f32x4 acc[10];
    #pragma unroll
    for (int i = 0; i < 10; ++i)
        acc[i] = __builtin_amdgcn_mfma_f32_16x16x32_f16(
            afrag[i][0], bf[0], gxf, 0, 0, 0);
    #pragma unroll
    for (int kt = 1; kt < 5; ++kt)
        #pragma unroll
        for (int i = 0; i < 10; ++i)
            acc[i] = __builtin_amdgcn_mfma_f32_16x16x32_f16(
                afrag[i][kt], bf[kt], acc[i], 0, 0, 0);

    // 4) Select this lane's tile (sel = col for col<10).
    float g0 = acc[0][0], g1 = acc[0][1], g2 = acc[0][2], g3 = acc[0][3];
    #pragma unroll
    for (int i = 1; i < 10; ++i) {
        const bool p = (sel == i);
        g0 = p ? acc[i][0] : g0;
        g1 = p ? acc[i][1] : g1;
        g2 = p ? acc[i][2] : g2;
        g3 = p ? acc[i][3] : g3;
    }

    // 5) Activation (pre-scaled args; direct form).
    const float ei = __builtin_amdgcn_exp2f(fminf(g0, 38.f));   // e^{-i}
    const float ef = __builtin_amdgcn_exp2f(fminf(g1, 38.f));   // e^{-f}
    const float eg = __builtin_amdgcn_exp2f(fminf(g2, 38.f));   // e^{2g}
    const float eo = __builtin_amdgcn_exp2f(fminf(g3, 38.f));   // e^{-o}
    const float sig_i = __builtin_amdgcn_rcpf(1.f + ei);
    const float sig_f = __builtin_amdgcn_rcpf(1.f + ef);
    const float sig_o = __builtin_amdgcn_rcpf(1.f + eo);
    const float tng   = (eg - 1.f) * __builtin_amdgcn_rcpf(eg + 1.f);
    const float c = sig_f * cst + sig_i * tng;
    cst = c;
    const float ec = __builtin_amdgcn_exp2f(fminf(K2 * c, 80.f));
    const float tnc = (ec - 1.f) * __builtin_amdgcn_rcpf(ec + 1.f);
    if (wr) hbufs[(cur ^ 1) * 160 + wel] = (f16)(sig_o * tnc);

    // 6) Drain LDS ops only; ONE raw barrier per step (vmcnt stays hot).
    asm volatile("s_waitcnt lgkmcnt(0)" ::: "memory");
    __builtin_amdgcn_s_barrier();
    __builtin_amdgcn_sched_barrier(0);
}

__global__ __launch_bounds__(256, 1) void lstm_scan(
    const f16* __restrict__ gates3, const f16* __restrict__ whhf,
    const float* __restrict__ last_w, const float* __restrict__ last_b,
    float* __restrict__ out)
{
    __shared__ __align__(16) f16 hbufs[2 * 160];   // linear h, double-buffered
    const int b = blockIdx.x;
    const int tid = threadIdx.x, w = tid >> 6, lane = tid & 63;
    const int col = lane & 15, grp = lane >> 4;
    const int sel = (col < 10) ? col : col - 10;   // cols 10-15 redundant
    const bool wr = (col < 10);
    const int wel = 40 * w + 4 * sel + grp;        // h index this lane writes

    for (int i = tid; i < 2 * 160; i += 256) hbufs[i] = (f16)0.f;

    // w_hh A-fragments: 10 tiles x 5 kt (200 VGPRs, 1 wave/SIMD budget 512).
    f32x4 afrag[10][5];
    #pragma unroll
    for (int i = 0; i < 10; ++i)
        #pragma unroll
        for (int kt = 0; kt < 5; ++kt)
            afrag[i][kt] =
                *(const f32x4*)(whhf + (size_t)((((10 * w + i) * 5) + kt) * 64 + lane) * 8);

    float cst = 0.f;
    __syncthreads();

    // This lane's unit-gates column: col 160w + 16sel + 4grp (+G in 0..3).
    const f16* gbu = gates3 + (size_t)b * NCOL + 160 * w + 16 * sel + 4 * grp;

    f16x4 pA = *(const f16x4*)(gbu);
    f16x4 pB = *(const f16x4*)(gbu + (size_t)1 * GSTEP);
    const f16* pLoad = gbu + (size_t)2 * GSTEP;    // next to fetch: t = 2

    #pragma unroll 1
    for (int tb = 0; tb < TLEN; tb += 2) {
        lstm_stepZ(tb,     pA, pA, pLoad, afrag, hbufs, cst, grp, sel, wr, wel);
        lstm_stepZ(tb + 1, pB, pB, pLoad, afrag, hbufs, cst, grp, sel, wr, wel);
    }

    // Final projection (step 2047 wrote buffer 0; h is linear there).
    if (tid < 2) {
        float s = last_b[tid];
        for (int j = 0; j < 150; ++j)
            s += (float)hbufs[j] * last_w[tid * 150 + j];
        out[b * 2 + tid] = s;
    }
}

// ---------------------------------------------------------------------------
extern "C" void kernel_launch(void* const* d_in, const int* in_sizes, int n_in,
                              void* d_out, int out_size, void* d_ws, size_t ws_size,
                              hipStream_t stream) {
    const float* inp    = (const float*)d_in[0];
    const float* conv_w = (const float*)d_in[1];
    const float* conv_b = (const float*)d_in[2];
    const float* w_ih   = (const float*)d_in[3];
    const float* w_hh   = (const float*)d_in[4];
    const float* b_ih   = (const float*)d_in[5];
    const float* b_hh   = (const float*)d_in[6];
    const float* last_w = (const float*)d_in[7];
    const float* last_b = (const float*)d_in[8];
    float* out = (float*)d_out;

    char* ws = (char*)d_ws;
    f16*   y      = (f16*)(ws);                        // 32768*160*2   = 10,485,760 B
    f16*   gates3 = (f16*)(ws + 10485760);             // 2050*16*640*2 = 41,984,000 B
    f16*   wihf   = (f16*)(ws + 10485760 + 41984000);          // 204,800 B
    f16*   whhf   = (f16*)(ws + 10485760 + 41984000 + 204800); // 204,800 B
    float* biasp  = (float*)(ws + 10485760 + 41984000 + 409600); // 2,560 B

    prep_weights<<<120, 256, 0, stream>>>(w_ih, w_hh, b_ih, b_hh, wihf, whhf, biasp);
    conv_relu<<<8192, 256, 0, stream>>>(inp, conv_w, conv_b, y);
    gates_gemm<<<256, 640, 0, stream>>>(y, wihf, biasp, gates3);
    lstm_scan<<<16, 256, 0, stream>>>(gates3, whhf, last_w, last_b, out);
}

// Round 11
// 1364.305 us; speedup vs baseline: 1.1920x; 1.1920x over previous
//
#include <hip/hip_runtime.h>

typedef _Float16 f16;
typedef _Float16 f16x4 __attribute__((ext_vector_type(4)));
typedef _Float16 f16x8 __attribute__((ext_vector_type(8)));
typedef float f32x4 __attribute__((ext_vector_type(4)));

#define TLEN 2048
#define TPAD 2050     // gates3 time extent (2 pad steps: prefetch needs no clamp)
#define NCOL 640      // padded columns: 160 units x 4 gates, col = u*4 + G
#define GSTEP (16 * NCOL)   // f16 elements per timestep in gates3 [t][b][col]
#define K1   1.4426950408889634f   // log2(e)
#define K2   2.8853900817779268f   // 2*log2(e)

__device__ __forceinline__ f16x8 as_f16x8(f32x4 v) {
    union { f32x4 f; f16x8 h; } u; u.f = v; return u.h;
}

// ---------------------------------------------------------------------------
// Prep: MFMA fragment-ordered fp16 w_ih / w_hh, columns ordered
// col = unit*4 + gate, PRE-SCALED per gate (i,f,o: -K1; g: +K2) so the
// scan's exp2 args need no multiply.  Fragment layout:
// [nt(40)][kt(5)][lane(64)][e(8)], col = nt*16 + (lane&15),
// k = kt*32 + (lane>>4)*8 + e.  biasp[col] gets the same scale.
// ---------------------------------------------------------------------------
__global__ void prep_weights(const float* __restrict__ w_ih,
                             const float* __restrict__ w_hh,
                             const float* __restrict__ b_ih,
                             const float* __restrict__ b_hh,
                             f16* __restrict__ wihf, f16* __restrict__ whhf,
                             float* __restrict__ biasp)
{
    const int idx = blockIdx.x * blockDim.x + threadIdx.x;
    const int stride = gridDim.x * blockDim.x;
    for (int i = idx; i < 40 * 5 * 64 * 8; i += stride) {
        const int e = i & 7;
        const int lane = (i >> 3) & 63;
        const int kt = (i >> 9) % 5;
        const int nt = i / 2560;
        const int colg = nt * 16 + (lane & 15);
        const int u = colg >> 2, G = colg & 3;
        const int k = kt * 32 + (lane >> 4) * 8 + e;
        const float sc = (G == 2) ? K2 : -K1;
        f16 vi = (f16)0.f, vh = (f16)0.f;
        if (u < 150) {
            const int row = G * 150 + u;
            if (k < 144) vi = (f16)(w_ih[row * 144 + k] * sc);
            if (k < 150) vh = (f16)(w_hh[row * 150 + k] * sc);
        }
        wihf[i] = vi;
        whhf[i] = vh;
    }
    for (int i = idx; i < NCOL; i += stride) {
        const int u = i >> 2, G = i & 3;
        const float sc = (G == 2) ? K2 : -K1;
        biasp[i] = (u < 150) ? (b_ih[G * 150 + u] + b_hh[G * 150 + u]) * sc : 0.f;
    }
}

// ---------------------------------------------------------------------------
// Conv 3x3 VALID (17->4) + bias + ReLU.  4 (b,t) tiles per 256-thread block.
// Writes y in [t*16+b][160] fp16 (K padded 144->160 with zeros).
// ---------------------------------------------------------------------------
__global__ __launch_bounds__(256) void conv_relu(
    const float* __restrict__ in, const float* __restrict__ cw,
    const float* __restrict__ cb, f16* __restrict__ y)
{
    __shared__ float s_in[4][1088];
    __shared__ float s_w[612];
    __shared__ float s_b[4];
    const int tid = threadIdx.x, sub = tid >> 6, lt = tid & 63;
    const int bt = blockIdx.x * 4 + sub;
    const float* ip = in + (size_t)bt * 1088;
    #pragma unroll
    for (int i = 0; i < 17; ++i) s_in[sub][lt + i * 64] = ip[lt + i * 64];
    for (int i = tid; i < 612; i += 256) s_w[i] = cw[i];
    if (tid < 4) s_b[tid] = cb[tid];
    __syncthreads();
    const int b = bt >> 11, t = bt & 2047;
    f16* yr = y + (size_t)(t * 16 + b) * 160;
    for (int i = lt; i < 160; i += 64) {
        float v = 0.f;
        if (i < 144) {
            const int oc = i / 36, rr = i % 36, oy = rr / 6, ox = rr % 6;
            float acc = s_b[oc];
            const float* wp = s_w + oc * 153;
            const float* bp = &s_in[sub][oy * 8 + ox];
            #pragma unroll
            for (int ic = 0; ic < 17; ++ic)
                #pragma unroll
                for (int ky = 0; ky < 3; ++ky)
                    #pragma unroll
                    for (int kx = 0; kx < 3; ++kx)
                        acc += bp[ic * 64 + ky * 8 + kx] * wp[ic * 9 + ky * 3 + kx];
            v = fmaxf(acc, 0.f);
        }
        yr[i] = (f16)v;
    }
}

// ---------------------------------------------------------------------------
// gates_x = y @ w_ih_scaled^T + bias_scaled.  One block (10 waves) per 8
// timesteps: w_ih fragments + bias hoisted into registers once, then 8 t's
// of {load A, 20 MFMA, store} -- cuts wihf L2 re-reads 8x vs one-t blocks.
// Output layout [t][b(16)][col(640)] flat f16.
// ---------------------------------------------------------------------------
__global__ __launch_bounds__(640, 1) void gates_gemm(
    const f16* __restrict__ y, const f16* __restrict__ wihf,
    const float* __restrict__ biasp, f16* __restrict__ gates3)
{
    const int tid = threadIdx.x, wv = tid >> 6, lane = tid & 63;
    const int col = lane & 15, grp = lane >> 4;
    const int t0 = blockIdx.x * 8;

    f16x8 bfr[4][5];
    float bb[4];
    #pragma unroll
    for (int i = 0; i < 4; ++i) {
        const int nt = wv * 4 + i;
        const f16* wf = wihf + (size_t)(nt * 5) * 512;
        #pragma unroll
        for (int kt = 0; kt < 5; ++kt)
            bfr[i][kt] = *(const f16x8*)(wf + kt * 512 + lane * 8);
        bb[i] = biasp[nt * 16 + col];
    }

    for (int t = t0; t < t0 + 8; ++t) {
        f16x8 a[5];
        const f16* yr = y + (size_t)(t * 16 + col) * 160;
        #pragma unroll
        for (int kt = 0; kt < 5; ++kt)
            a[kt] = *(const f16x8*)(yr + kt * 32 + grp * 8);
        #pragma unroll
        for (int i = 0; i < 4; ++i) {
            const int nt = wv * 4 + i;
            f32x4 acc = {0.f, 0.f, 0.f, 0.f};
            #pragma unroll
            for (int kt = 0; kt < 5; ++kt)
                acc = __builtin_amdgcn_mfma_f32_16x16x32_f16(a[kt], bfr[i][kt], acc, 0, 0, 0);
            const int colg = nt * 16 + col;
            #pragma unroll
            for (int r = 0; r < 4; ++r)
                gates3[((size_t)(t * 16 + grp * 4 + r)) * NCOL + colg] = (f16)(acc[r] + bb[i]);
        }
    }
}

// ---------------------------------------------------------------------------
// Batch-parallel persistent LSTM scan: 16 WGs (one batch row each), 512
// threads = 8 waves = 2 waves/SIMD -- the proven optimum (r9): balanced
// 50 MFMA/SIMD/step AND a sibling wave to hide each wave's serial tail
// (r10 showed 1 wave/SIMD exposes the tail, costing more than its saved
// duplicate issue).  A = w_hh fragments resident; B = h broadcast from a
// linear 160-f16 LDS double buffer (conflict-free).  Each lane loads ONE
// f16x4 of gates_x (its own unit), converted in the B-read shadow; shared
// C-init for all tiles' kt=0 (unselected results discarded by the select).
// Trims vs r9: cur passed as literal 0/1 (no per-step t&1 + address math);
// no clamps on i/f/o exp args (rcp(inf)=0 gives the exact sigmoid limit;
// only tanh args need clamping to avoid inf*0=NaN); t+2 prefetch issued
// first.  One raw barrier per step; vmcnt never drained.
// ---------------------------------------------------------------------------
__device__ __forceinline__ void lstm_stepY(
    int t, int cur, f16x4& pfu, f16x4& pfc, const f16*& pLoad,
    const f32x4 (&afrag)[5][5], f16* hbufs, float& cst,
    int grp, int sel, bool wr, int wel)
{
    // 1) Issue next-next-step gates load first (longest latency, 2-step lead).
    const f16x4 pnew = *(const f16x4*)pLoad;
    pLoad += GSTEP;

    // 2) B-fragment reads (broadcast, conflict-free).
    const f16* hr = hbufs + cur * 160 + grp * 8;
    f16x8 bf[5];
    #pragma unroll
    for (int kt = 0; kt < 5; ++kt)
        bf[kt] = *(const f16x8*)(hr + kt * 32);

    // 3) In the read shadow: convert this step's unit-gates (loaded 2 steps
    //    ago) to f32.
    f32x4 gxf;
    gxf[0] = (float)pfu[0];
    gxf[1] = (float)pfu[1];
    gxf[2] = (float)pfu[2];
    gxf[3] = (float)pfu[3];
    pfc = pnew;

    // 4) MFMA: kt=0 uses gxf as C-in for ALL tiles (only the selected
    //    tile's result is consumed); kt=1..4 chain.
    f32x4 acc[5];
    #pragma unroll
    for (int i = 0; i < 5; ++i)
        acc[i] = __builtin_amdgcn_mfma_f32_16x16x32_f16(
            afrag[i][0], bf[0], gxf, 0, 0, 0);
    #pragma unroll
    for (int kt = 1; kt < 5; ++kt)
        #pragma unroll
        for (int i = 0; i < 5; ++i)
            acc[i] = __builtin_amdgcn_mfma_f32_16x16x32_f16(
                afrag[i][kt], bf[kt], acc[i], 0, 0, 0);

    // 5) Select this lane's tile (sel = col mod 5; masks loop-invariant).
    float g0 = acc[0][0], g1 = acc[0][1], g2 = acc[0][2], g3 = acc[0][3];
    #pragma unroll
    for (int i = 1; i < 5; ++i) {
        const bool p = (sel == i);
        g0 = p ? acc[i][0] : g0;
        g1 = p ? acc[i][1] : g1;
        g2 = p ? acc[i][2] : g2;
        g3 = p ? acc[i][3] : g3;
    }

    // 6) Activation.  Pre-scaled args (exp2 direct).  i/f/o need no clamp:
    //    exp2->inf gives rcp(1+inf)=0, the exact sigmoid limit, no NaN.
    //    Only tanh forms ((e-1)*rcp(e+1)) clamp their exp arg.
    const float ei = __builtin_amdgcn_exp2f(g0);                // e^{-i}
    const float ef = __builtin_amdgcn_exp2f(g1);                // e^{-f}
    const float eg = __builtin_amdgcn_exp2f(fminf(g2, 38.f));   // e^{2g}
    const float eo = __builtin_amdgcn_exp2f(g3);                // e^{-o}
    const float sig_i = __builtin_amdgcn_rcpf(1.f + ei);
    const float sig_f = __builtin_amdgcn_rcpf(1.f + ef);
    const float sig_o = __builtin_amdgcn_rcpf(1.f + eo);
    const float tng   = (eg - 1.f) * __builtin_amdgcn_rcpf(eg + 1.f);
    const float c = sig_f * cst + sig_i * tng;
    cst = c;
    const float ec = __builtin_amdgcn_exp2f(fminf(K2 * c, 80.f));
    const float tnc = (ec - 1.f) * __builtin_amdgcn_rcpf(ec + 1.f);
    if (wr) hbufs[(cur ^ 1) * 160 + wel] = (f16)(sig_o * tnc);

    // 7) Drain LDS ops only; ONE raw barrier per step (vmcnt stays hot).
    asm volatile("s_waitcnt lgkmcnt(0)" ::: "memory");
    __builtin_amdgcn_s_barrier();
    __builtin_amdgcn_sched_barrier(0);
}

__global__ __launch_bounds__(512, 1) void lstm_scan(
    const f16* __restrict__ gates3, const f16* __restrict__ whhf,
    const float* __restrict__ last_w, const float* __restrict__ last_b,
    float* __restrict__ out)
{
    __shared__ __align__(16) f16 hbufs[2 * 160];   // linear h, double-buffered
    const int b = blockIdx.x;
    const int tid = threadIdx.x, w = tid >> 6, lane = tid & 63;
    const int col = lane & 15, grp = lane >> 4;
    const int sel = (col < 5) ? col : ((col < 10) ? col - 5 : ((col < 15) ? col - 10 : 0));
    const bool wr = (col < 5);
    const int wel = 20 * w + 4 * sel + grp;        // h index this lane writes

    for (int i = tid; i < 2 * 160; i += 512) hbufs[i] = (f16)0.f;

    // w_hh A-fragments for this wave's 5 tiles (resident in VGPR/AGPR file).
    f32x4 afrag[5][5];
    #pragma unroll
    for (int i = 0; i < 5; ++i)
        #pragma unroll
        for (int kt = 0; kt < 5; ++kt)
            afrag[i][kt] =
                *(const f32x4*)(whhf + (size_t)((((5 * w + i) * 5) + kt) * 64 + lane) * 8);

    float cst = 0.f;
    __syncthreads();

    // This lane's unit-gates column: col 80w + 16sel + 4grp (+G in 0..3).
    const f16* gbu = gates3 + (size_t)b * NCOL + 80 * w + 16 * sel + 4 * grp;

    f16x4 pA = *(const f16x4*)(gbu);
    f16x4 pB = *(const f16x4*)(gbu + (size_t)1 * GSTEP);
    const f16* pLoad = gbu + (size_t)2 * GSTEP;    // next to fetch: t = 2

    #pragma unroll 1
    for (int tb = 0; tb < TLEN; tb += 2) {
        lstm_stepY(tb,     0, pA, pA, pLoad, afrag, hbufs, cst, grp, sel, wr, wel);
        lstm_stepY(tb + 1, 1, pB, pB, pLoad, afrag, hbufs, cst, grp, sel, wr, wel);
    }

    // Final projection (step 2047 wrote buffer 0; h is linear there).
    if (tid < 2) {
        float s = last_b[tid];
        for (int j = 0; j < 150; ++j)
            s += (float)hbufs[j] * last_w[tid * 150 + j];
        out[b * 2 + tid] = s;
    }
}

// ---------------------------------------------------------------------------
extern "C" void kernel_launch(void* const* d_in, const int* in_sizes, int n_in,
                              void* d_out, int out_size, void* d_ws, size_t ws_size,
                              hipStream_t stream) {
    const float* inp    = (const float*)d_in[0];
    const float* conv_w = (const float*)d_in[1];
    const float* conv_b = (const float*)d_in[2];
    const float* w_ih   = (const float*)d_in[3];
    const float* w_hh   = (const float*)d_in[4];
    const float* b_ih   = (const float*)d_in[5];
    const float* b_hh   = (const float*)d_in[6];
    const float* last_w = (const float*)d_in[7];
    const float* last_b = (const float*)d_in[8];
    float* out = (float*)d_out;

    char* ws = (char*)d_ws;
    f16*   y      = (f16*)(ws);                        // 32768*160*2   = 10,485,760 B
    f16*   gates3 = (f16*)(ws + 10485760);             // 2050*16*640*2 = 41,984,000 B
    f16*   wihf   = (f16*)(ws + 10485760 + 41984000);          // 204,800 B
    f16*   whhf   = (f16*)(ws + 10485760 + 41984000 + 204800); // 204,800 B
    float* biasp  = (float*)(ws + 10485760 + 41984000 + 409600); // 2,560 B

    prep_weights<<<120, 256, 0, stream>>>(w_ih, w_hh, b_ih, b_hh, wihf, whhf, biasp);
    conv_relu<<<8192, 256, 0, stream>>>(inp, conv_w, conv_b, y);
    gates_gemm<<<256, 640, 0, stream>>>(y, wihf, biasp, gates3);
    lstm_scan<<<16, 512, 0, stream>>>(gates3, whhf, last_w, last_b, out);
}

// Round 12
// 1091.947 us; speedup vs baseline: 1.4893x; 1.2494x over previous
//
#include <hip/hip_runtime.h>

typedef _Float16 f16;
typedef _Float16 f16x4 __attribute__((ext_vector_type(4)));
typedef _Float16 f16x8 __attribute__((ext_vector_type(8)));
typedef float f32x4 __attribute__((ext_vector_type(4)));
typedef int i32x4 __attribute__((ext_vector_type(4)));

#define TLEN 2048
#define TPAD 2050     // gates3 time extent (2 pad steps: prefetch needs no clamp)
#define NCOL 640      // padded columns: 160 units x 4 gates, col = u*4 + G
#define GSTEP (16 * NCOL)   // f16 elements per timestep in gates3 [t][b][col]
#define K1   1.4426950408889634f   // log2(e)
#define K2   2.8853900817779268f   // 2*log2(e)

// ---------------------------------------------------------------------------
// Per-row absolute max of w_hh (600 rows x 150) for i8 quantization scales.
// ---------------------------------------------------------------------------
__global__ __launch_bounds__(64) void rowmax_k(const float* __restrict__ w_hh,
                                               float* __restrict__ rowmax)
{
    const int r = blockIdx.x * 64 + threadIdx.x;
    if (r < 600) {
        float m = 0.f;
        for (int k = 0; k < 150; ++k) m = fmaxf(m, fabsf(w_hh[r * 150 + k]));
        rowmax[r] = m;
    }
}

// ---------------------------------------------------------------------------
// Prep:
//  - wihf: f16 MFMA B-fragments of w_ih, PRE-SCALED per gate (i,f,o: -K1;
//    g: +K2), col order u*4+G.  [nt(40)][kt(5)][lane(64)][e(8)],
//    col = nt*16+(lane&15), k = kt*32+(lane>>4)*8+e.  (For gates_gemm.)
//  - biasp: (b_ih+b_hh) with the same per-gate prescale.
//  - whhq: i8 MFMA A-fragments of w_hh for the scan, per-ROW quantized
//    (q = rint(w*127/rowmax[row])), K padded 150->192 (3 kt of 64).
//    [nt(40)][kt(3)][lane(64)][byte(16)], col = nt*16+(lane&15),
//    k = kt*64+(lane>>4)*16+byte.  Same assumed k-map used for h packing in
//    the scan, so any HW k-permutation cancels.
//  - dsc[col]: dequant scale = gate_sc(G) * rowmax[row] / (127*127).
// ---------------------------------------------------------------------------
__global__ void prep_weights(const float* __restrict__ w_ih,
                             const float* __restrict__ w_hh,
                             const float* __restrict__ b_ih,
                             const float* __restrict__ b_hh,
                             const float* __restrict__ rowmax,
                             f16* __restrict__ wihf, signed char* __restrict__ whhq,
                             float* __restrict__ biasp, float* __restrict__ dsc)
{
    const int idx = blockIdx.x * blockDim.x + threadIdx.x;
    const int stride = gridDim.x * blockDim.x;
    // w_ih f16 fragments (prescaled)
    for (int i = idx; i < 40 * 5 * 64 * 8; i += stride) {
        const int e = i & 7;
        const int lane = (i >> 3) & 63;
        const int kt = (i >> 9) % 5;
        const int nt = i / 2560;
        const int colg = nt * 16 + (lane & 15);
        const int u = colg >> 2, G = colg & 3;
        const int k = kt * 32 + (lane >> 4) * 8 + e;
        const float sc = (G == 2) ? K2 : -K1;
        f16 vi = (f16)0.f;
        if (u < 150 && k < 144) vi = (f16)(w_ih[(G * 150 + u) * 144 + k] * sc);
        wihf[i] = vi;
    }
    // w_hh i8 fragments (raw, per-row scale; gate prescale folded into dsc)
    for (int i = idx; i < 40 * 3 * 64 * 16; i += stride) {
        const int byte = i & 15;
        const int lane = (i >> 4) & 63;
        const int kt = (i >> 10) % 3;
        const int nt = i / 3072;
        const int colg = nt * 16 + (lane & 15);
        const int u = colg >> 2, G = colg & 3;
        const int k = kt * 64 + (lane >> 4) * 16 + byte;
        signed char q = 0;
        if (u < 150 && k < 150) {
            const int row = G * 150 + u;
            const float rm = rowmax[row];
            if (rm > 0.f)
                q = (signed char)(int)rintf(w_hh[row * 150 + k] * (127.f / rm));
        }
        whhq[i] = q;
    }
    // bias (prescaled) and dequant scales
    for (int i = idx; i < NCOL; i += stride) {
        const int u = i >> 2, G = i & 3;
        const float sc = (G == 2) ? K2 : -K1;
        biasp[i] = (u < 150) ? (b_ih[G * 150 + u] + b_hh[G * 150 + u]) * sc : 0.f;
        dsc[i]   = (u < 150) ? sc * rowmax[G * 150 + u] * (1.f / 16129.f) : 0.f;
    }
}

// ---------------------------------------------------------------------------
// Conv 3x3 VALID (17->4) + bias + ReLU.  4 (b,t) tiles per 256-thread block.
// Writes y in [t*16+b][160] fp16 (K padded 144->160 with zeros).
// ---------------------------------------------------------------------------
__global__ __launch_bounds__(256) void conv_relu(
    const float* __restrict__ in, const float* __restrict__ cw,
    const float* __restrict__ cb, f16* __restrict__ y)
{
    __shared__ float s_in[4][1088];
    __shared__ float s_w[612];
    __shared__ float s_b[4];
    const int tid = threadIdx.x, sub = tid >> 6, lt = tid & 63;
    const int bt = blockIdx.x * 4 + sub;
    const float* ip = in + (size_t)bt * 1088;
    #pragma unroll
    for (int i = 0; i < 17; ++i) s_in[sub][lt + i * 64] = ip[lt + i * 64];
    for (int i = tid; i < 612; i += 256) s_w[i] = cw[i];
    if (tid < 4) s_b[tid] = cb[tid];
    __syncthreads();
    const int b = bt >> 11, t = bt & 2047;
    f16* yr = y + (size_t)(t * 16 + b) * 160;
    for (int i = lt; i < 160; i += 64) {
        float v = 0.f;
        if (i < 144) {
            const int oc = i / 36, rr = i % 36, oy = rr / 6, ox = rr % 6;
            float acc = s_b[oc];
            const float* wp = s_w + oc * 153;
            const float* bp = &s_in[sub][oy * 8 + ox];
            #pragma unroll
            for (int ic = 0; ic < 17; ++ic)
                #pragma unroll
                for (int ky = 0; ky < 3; ++ky)
                    #pragma unroll
                    for (int kx = 0; kx < 3; ++kx)
                        acc += bp[ic * 64 + ky * 8 + kx] * wp[ic * 9 + ky * 3 + kx];
            v = fmaxf(acc, 0.f);
        }
        yr[i] = (f16)v;
    }
}

// ---------------------------------------------------------------------------
// gates_x = y @ w_ih_scaled^T + bias_scaled.  One block (10 waves) per 8
// timesteps: w_ih fragments + bias hoisted once.  Output [t][b(16)][col(640)].
// ---------------------------------------------------------------------------
__global__ __launch_bounds__(640, 1) void gates_gemm(
    const f16* __restrict__ y, const f16* __restrict__ wihf,
    const float* __restrict__ biasp, f16* __restrict__ gates3)
{
    const int tid = threadIdx.x, wv = tid >> 6, lane = tid & 63;
    const int col = lane & 15, grp = lane >> 4;
    const int t0 = blockIdx.x * 8;

    f16x8 bfr[4][5];
    float bb[4];
    #pragma unroll
    for (int i = 0; i < 4; ++i) {
        const int nt = wv * 4 + i;
        const f16* wf = wihf + (size_t)(nt * 5) * 512;
        #pragma unroll
        for (int kt = 0; kt < 5; ++kt)
            bfr[i][kt] = *(const f16x8*)(wf + kt * 512 + lane * 8);
        bb[i] = biasp[nt * 16 + col];
    }

    for (int t = t0; t < t0 + 8; ++t) {
        f16x8 a[5];
        const f16* yr = y + (size_t)(t * 16 + col) * 160;
        #pragma unroll
        for (int kt = 0; kt < 5; ++kt)
            a[kt] = *(const f16x8*)(yr + kt * 32 + grp * 8);
        #pragma unroll
        for (int i = 0; i < 4; ++i) {
            const int nt = wv * 4 + i;
            f32x4 acc = {0.f, 0.f, 0.f, 0.f};
            #pragma unroll
            for (int kt = 0; kt < 5; ++kt)
                acc = __builtin_amdgcn_mfma_f32_16x16x32_f16(a[kt], bfr[i][kt], acc, 0, 0, 0);
            const int colg = nt * 16 + col;
            #pragma unroll
            for (int r = 0; r < 4; ++r)
                gates3[((size_t)(t * 16 + grp * 4 + r)) * NCOL + colg] = (f16)(acc[r] + bb[i]);
        }
    }
}

// ---------------------------------------------------------------------------
// Batch-parallel persistent LSTM scan, i8 MFMA edition.  16 WGs (one batch
// row each), 512 threads = 8 waves = 2/SIMD (proven optimum r9-r11).
// K=64 per MFMA (i8) cuts the per-step instruction count 200->120: floor
// 970->612 cyc/SIMD.  A = per-row-quantized w_hh i8 fragments (resident);
// B = h quantized to i8 at scale 127 (h in (-1,1) exactly), broadcast from
// a linear 192-byte LDS double buffer.  c-state stays f32 in registers;
// gates_x stays f16 and is added in the f32 epilogue with the per-col
// dequant scale (gate prescale folded in).  h also written once as f16 on
// the last step for the final projection.  One raw barrier per step;
// global gates prefetch 2 steps ahead, vmcnt never drained.
// ---------------------------------------------------------------------------
__device__ __forceinline__ void lstm_stepQ(
    int t, int cur, f16x4& pfu, f16x4& pfc, const f16*& pLoad,
    const i32x4 (&afrag)[5][3], const f32x4& scv,
    signed char* hqs, f16* hfs, float& cst,
    int grp, int sel, bool wr, int u)
{
    // 1) Issue next-next-step gates load first (longest latency).
    const f16x4 pnew = *(const f16x4*)pLoad;
    pLoad += GSTEP;

    // 2) B-fragment reads: 3 x b128 of quantized h (broadcast, conflict-free).
    const signed char* hr = hqs + cur * 192 + grp * 16;
    i32x4 bf[3];
    #pragma unroll
    for (int kt = 0; kt < 3; ++kt)
        bf[kt] = *(const i32x4*)(hr + kt * 64);

    // 3) In the read shadow: convert this step's unit-gates (f16->f32).
    float gx0 = (float)pfu[0], gx1 = (float)pfu[1];
    float gx2 = (float)pfu[2], gx3 = (float)pfu[3];
    pfc = pnew;

    // 4) i8 MFMA: 5 tiles x 3 kt, integer C-init 0.
    const i32x4 zc = {0, 0, 0, 0};
    i32x4 acc[5];
    #pragma unroll
    for (int i = 0; i < 5; ++i)
        acc[i] = __builtin_amdgcn_mfma_i32_16x16x64_i8(afrag[i][0], bf[0], zc, 0, 0, 0);
    #pragma unroll
    for (int kt = 1; kt < 3; ++kt)
        #pragma unroll
        for (int i = 0; i < 5; ++i)
            acc[i] = __builtin_amdgcn_mfma_i32_16x16x64_i8(afrag[i][kt], bf[kt], acc[i], 0, 0, 0);

    // 5) Select this lane's tile (i32 cndmasks).
    int s0 = acc[0][0], s1 = acc[0][1], s2 = acc[0][2], s3 = acc[0][3];
    #pragma unroll
    for (int i = 1; i < 5; ++i) {
        const bool p = (sel == i);
        s0 = p ? acc[i][0] : s0;
        s1 = p ? acc[i][1] : s1;
        s2 = p ? acc[i][2] : s2;
        s3 = p ? acc[i][3] : s3;
    }

    // 6) Dequant + add gates_x: g = acc * dsc + gx  (dsc carries gate sign).
    const float g0 = fmaf((float)s0, scv[0], gx0);
    const float g1 = fmaf((float)s1, scv[1], gx1);
    const float g2 = fmaf((float)s2, scv[2], gx2);
    const float g3 = fmaf((float)s3, scv[3], gx3);

    // 7) Activation (pre-scaled args; rcp(inf)=0 handles i/f/o saturation).
    const float ei = __builtin_amdgcn_exp2f(g0);                // e^{-i}
    const float ef = __builtin_amdgcn_exp2f(g1);                // e^{-f}
    const float eg = __builtin_amdgcn_exp2f(fminf(g2, 38.f));   // e^{2g}
    const float eo = __builtin_amdgcn_exp2f(g3);                // e^{-o}
    const float sig_i = __builtin_amdgcn_rcpf(1.f + ei);
    const float sig_f = __builtin_amdgcn_rcpf(1.f + ef);
    const float sig_o = __builtin_amdgcn_rcpf(1.f + eo);
    const float tng   = (eg - 1.f) * __builtin_amdgcn_rcpf(eg + 1.f);
    const float c = sig_f * cst + sig_i * tng;
    cst = c;
    const float ec = __builtin_amdgcn_exp2f(fminf(K2 * c, 80.f));
    const float tnc = (ec - 1.f) * __builtin_amdgcn_rcpf(ec + 1.f);
    const float h = sig_o * tnc;

    // 8) Quantize + write h (i8); f16 copy only on the last step.
    if (wr) hqs[(cur ^ 1) * 192 + u] = (signed char)(int)rintf(127.f * h);
    if (t == TLEN - 1 && wr) hfs[u] = (f16)h;

    // 9) Drain LDS ops only; ONE raw barrier per step (vmcnt stays hot).
    asm volatile("s_waitcnt lgkmcnt(0)" ::: "memory");
    __builtin_amdgcn_s_barrier();
    __builtin_amdgcn_sched_barrier(0);
}

__global__ __launch_bounds__(512, 1) void lstm_scan(
    const f16* __restrict__ gates3, const signed char* __restrict__ whhq,
    const float* __restrict__ dsc,
    const float* __restrict__ last_w, const float* __restrict__ last_b,
    float* __restrict__ out)
{
    __shared__ __align__(16) signed char hq[2 * 192];  // i8 h, double-buffered
    __shared__ __align__(16) f16 hf[160];              // f16 h (last step only)
    const int b = blockIdx.x;
    const int tid = threadIdx.x, w = tid >> 6, lane = tid & 63;
    const int col = lane & 15, grp = lane >> 4;
    const int sel = (col < 5) ? col : ((col < 10) ? col - 5 : ((col < 15) ? col - 10 : 0));
    const bool wr = (col < 5);
    const int u = 20 * w + 4 * sel + grp;          // h index this lane owns

    for (int i = tid; i < 2 * 192; i += 512) hq[i] = 0;

    // w_hh i8 A-fragments: 5 tiles x 3 kt (60 VGPRs of weights, resident).
    i32x4 afrag[5][3];
    #pragma unroll
    for (int i = 0; i < 5; ++i)
        #pragma unroll
        for (int kt = 0; kt < 3; ++kt)
            afrag[i][kt] =
                *(const i32x4*)(whhq + (size_t)(((5 * w + i) * 3 + kt) * 64 + lane) * 16);

    // Per-lane dequant scales for its unit's 4 gate columns.
    const f32x4 scv = *(const f32x4*)(dsc + 4 * u);

    float cst = 0.f;
    __syncthreads();

    // This lane's unit-gates column: col 80w + 16sel + 4grp (+G in 0..3).
    const f16* gbu = gates3 + (size_t)b * NCOL + 80 * w + 16 * sel + 4 * grp;

    f16x4 pA = *(const f16x4*)(gbu);
    f16x4 pB = *(const f16x4*)(gbu + (size_t)1 * GSTEP);
    const f16* pLoad = gbu + (size_t)2 * GSTEP;    // next to fetch: t = 2

    #pragma unroll 1
    for (int tb = 0; tb < TLEN; tb += 2) {
        lstm_stepQ(tb,     0, pA, pA, pLoad, afrag, scv, hq, hf, cst, grp, sel, wr, u);
        lstm_stepQ(tb + 1, 1, pB, pB, pLoad, afrag, scv, hq, hf, cst, grp, sel, wr, u);
    }

    // Final projection from the f16 h copy.
    if (tid < 2) {
        float s = last_b[tid];
        for (int j = 0; j < 150; ++j)
            s += (float)hf[j] * last_w[tid * 150 + j];
        out[b * 2 + tid] = s;
    }
}

// ---------------------------------------------------------------------------
extern "C" void kernel_launch(void* const* d_in, const int* in_sizes, int n_in,
                              void* d_out, int out_size, void* d_ws, size_t ws_size,
                              hipStream_t stream) {
    const float* inp    = (const float*)d_in[0];
    const float* conv_w = (const float*)d_in[1];
    const float* conv_b = (const float*)d_in[2];
    const float* w_ih   = (const float*)d_in[3];
    const float* w_hh   = (const float*)d_in[4];
    const float* b_ih   = (const float*)d_in[5];
    const float* b_hh   = (const float*)d_in[6];
    const float* last_w = (const float*)d_in[7];
    const float* last_b = (const float*)d_in[8];
    float* out = (float*)d_out;

    char* ws = (char*)d_ws;
    size_t off = 0;
    f16*   y      = (f16*)(ws + off);  off += 10485760;   // 32768*160*2
    f16*   gates3 = (f16*)(ws + off);  off += 41984000;   // 2050*16*640*2
    f16*   wihf   = (f16*)(ws + off);  off += 204800;     // 40*5*512*2
    signed char* whhq = (signed char*)(ws + off); off += 122880; // 40*3*1024
    float* biasp  = (float*)(ws + off); off += 2560;
    float* dsc    = (float*)(ws + off); off += 2560;
    float* rowmax = (float*)(ws + off); off += 2432;

    rowmax_k<<<10, 64, 0, stream>>>(w_hh, rowmax);
    prep_weights<<<120, 256, 0, stream>>>(w_ih, w_hh, b_ih, b_hh, rowmax,
                                          wihf, whhq, biasp, dsc);
    conv_relu<<<8192, 256, 0, stream>>>(inp, conv_w, conv_b, y);
    gates_gemm<<<256, 640, 0, stream>>>(y, wihf, biasp, gates3);
    lstm_scan<<<16, 512, 0, stream>>>(gates3, whhq, dsc, last_w, last_b, out);
}